// Round 1
// baseline (532.845 us; speedup 1.0000x reference)
//
#include <hip/hip_runtime.h>

// CustomModel_83794811945675: emb-lookup -> LSTM(64) over T=512 -> Dense(3) -> softmax
// Layout: 1 block per sequence (512 blocks x 256 threads = 4 waves).
//   lane = 4*(unit%16) + gate   (gate order i,f,g,o along 4H axis)
//   wave w owns hidden units [16w, 16w+16); each lane computes one z-column.
//   Wk/Wr columns held in registers (32+64 VGPRs); h,x double-buffered in LDS;
//   ONE __syncthreads per timestep; quad-local gate exchange via __shfl.

#define VOCAB 50000
#define EMB 32
#define HID 64
#define NCLS 3
#define BATCH 512
#define TSEQ 512

__global__ __launch_bounds__(256, 2) void lstm_fused_kernel(
    const int* __restrict__ tokens, const float* __restrict__ emb,
    const float* __restrict__ Wk, const float* __restrict__ Wr,
    const float* __restrict__ bias, const float* __restrict__ Wd,
    const float* __restrict__ bd, float* __restrict__ out)
{
    __shared__ __align__(16) float hbuf[2][HID];
    __shared__ __align__(16) float xbuf[2][EMB];
    __shared__ float lg[NCLS];

    const int tid  = threadIdx.x;
    const int wv   = tid >> 6;
    const int lane = tid & 63;
    const int ge   = lane & 3;           // 0:i 1:f 2:g 3:o
    const int u    = (wv << 4) + (lane >> 2);   // hidden unit 0..63
    const int col  = (ge << 6) + u;             // column in [0,256)
    const int seq  = blockIdx.x;
    const long tokbase = (long)seq * TSEQ;

    // activation: a = m1 * sigmoid(m1*z) + m0  ->  sigmoid (ge!=2) or tanh (ge==2)
    const float m1 = (ge == 2) ? 2.0f : 1.0f;
    const float m0 = (ge == 2) ? -1.0f : 0.0f;

    float wk[EMB];
#pragma unroll
    for (int k = 0; k < EMB; ++k) wk[k] = Wk[k * 256 + col];
    float wr[HID];
#pragma unroll
    for (int k = 0; k < HID; ++k) wr[k] = Wr[k * 256 + col];
    const float bz = bias[col];

    if (tid < HID) hbuf[0][tid] = 0.0f;
    if (tid < EMB) {
        const int tok0 = tokens[tokbase];
        xbuf[0][tid] = emb[(long)tok0 * EMB + tid];
    }

    float c = 0.0f, h = 0.0f;

    for (int t = 0; t < TSEQ; ++t) {
        const int cur = t & 1, nxt = cur ^ 1;
        __syncthreads();
        // prefetch x_{t+1} into the other buffer (wave 0, lanes 0..31)
        if (tid < EMB) {
            const int tn = (t + 1 < TSEQ) ? (t + 1) : t;
            const int tok = tokens[tokbase + tn];
            xbuf[nxt][tid] = emb[(long)tok * EMB + tid];
        }

        float z = bz;
#pragma unroll
        for (int kk = 0; kk < EMB / 4; ++kk) {
            const float4 x4 = *(const float4*)&xbuf[cur][kk * 4];
            z = fmaf(x4.x, wk[kk * 4 + 0], z);
            z = fmaf(x4.y, wk[kk * 4 + 1], z);
            z = fmaf(x4.z, wk[kk * 4 + 2], z);
            z = fmaf(x4.w, wk[kk * 4 + 3], z);
        }
#pragma unroll
        for (int kk = 0; kk < HID / 4; ++kk) {
            const float4 h4 = *(const float4*)&hbuf[cur][kk * 4];
            z = fmaf(h4.x, wr[kk * 4 + 0], z);
            z = fmaf(h4.y, wr[kk * 4 + 1], z);
            z = fmaf(h4.z, wr[kk * 4 + 2], z);
            z = fmaf(h4.w, wr[kk * 4 + 3], z);
        }

        // gate activation (branch-free: tanh(z) = 2*sigmoid(2z)-1)
        const float sg = 1.0f / (1.0f + __expf(-m1 * z));
        const float a  = fmaf(m1, sg, m0);

        // quad all-gather: lanes 4q..4q+3 hold i,f,g,o for unit q
        const int qb = lane & ~3;
        const float gi = __shfl(a, qb + 0, 64);
        const float gf = __shfl(a, qb + 1, 64);
        const float gg = __shfl(a, qb + 2, 64);
        const float go = __shfl(a, qb + 3, 64);

        c = fmaf(gf, c, gi * gg);                      // c = f*c + i*tanh(g)
        const float e2 = __expf(-2.0f * c);
        const float th = fmaf(2.0f, 1.0f / (1.0f + e2), -1.0f);  // tanh(c)
        h = go * th;
        if (ge == 0) hbuf[nxt][u] = h;                 // one writer per unit
    }

    __syncthreads();
    const float* hfin = hbuf[TSEQ & 1];

    if (tid < NCLS) {
        float acc = bd[tid];
#pragma unroll 8
        for (int k = 0; k < HID; ++k) acc = fmaf(hfin[k], Wd[k * NCLS + tid], acc);
        lg[tid] = acc;
    }
    __syncthreads();
    if (tid < NCLS) {
        const float l0 = lg[0], l1 = lg[1], l2 = lg[2];
        const float mm = fmaxf(l0, fmaxf(l1, l2));
        const float e0 = __expf(l0 - mm), e1 = __expf(l1 - mm), e2s = __expf(l2 - mm);
        out[seq * NCLS + tid] = __expf(lg[tid] - mm) / (e0 + e1 + e2s);
    }
}

extern "C" void kernel_launch(void* const* d_in, const int* in_sizes, int n_in,
                              void* d_out, int out_size, void* d_ws, size_t ws_size,
                              hipStream_t stream) {
    const int*   tokens = (const int*)  d_in[0];
    const float* emb    = (const float*)d_in[1];
    const float* Wk     = (const float*)d_in[2];
    const float* Wr     = (const float*)d_in[3];
    const float* b      = (const float*)d_in[4];
    const float* Wd     = (const float*)d_in[5];
    const float* bd     = (const float*)d_in[6];
    float* out = (float*)d_out;

    lstm_fused_kernel<<<dim3(BATCH), dim3(256), 0, stream>>>(
        tokens, emb, Wk, Wr, b, Wd, bd, out);
}

// Round 2
// 506.179 us; speedup vs baseline: 1.0527x; 1.0527x over previous
//
#include <hip/hip_runtime.h>

// CustomModel_83794811945675: emb-lookup -> LSTM(64) over T=512 -> Dense(3) -> softmax
// Layout: 1 block per sequence (512 blocks x 256 threads = 4 waves).
//   lane = 4*(unit%16) + gate (i,f,g,o); wave w owns units [16w,16w+16).
//   Wk/Wr columns pinned in VGPRs via amdgpu_waves_per_eu(2,2) (grid gives
//   exactly 2 waves/SIMD anyway, so capping max waves costs nothing and buys
//   a 256-VGPR budget so the 96 weight floats stay register-resident).
//   ONE __syncthreads per timestep; gate exchange via static ds_swizzle
//   quad-broadcast; tokens pre-staged in LDS so the x-prefetch is 1 global hop.

#define VOCAB 50000
#define EMB 32
#define HID 64
#define NCLS 3
#define BATCH 512
#define TSEQ 512

__device__ __forceinline__ float quad_bcast(float v, int imm_off) {
    // handled by caller with compile-time imm
    return v;
}

__global__ __launch_bounds__(256) __attribute__((amdgpu_waves_per_eu(2, 2)))
void lstm_fused_kernel(
    const int* __restrict__ tokens, const float* __restrict__ emb,
    const float* __restrict__ Wk, const float* __restrict__ Wr,
    const float* __restrict__ bias, const float* __restrict__ Wd,
    const float* __restrict__ bd, float* __restrict__ out)
{
    __shared__ __align__(16) float hbuf[2][HID];
    __shared__ __align__(16) float xbuf[2][EMB];
    __shared__ int tokbuf[TSEQ];
    __shared__ float lg[NCLS];

    const int tid  = threadIdx.x;
    const int wv   = tid >> 6;
    const int lane = tid & 63;
    const int ge   = lane & 3;                  // 0:i 1:f 2:g 3:o
    const int u    = (wv << 4) + (lane >> 2);   // hidden unit 0..63
    const int col  = (ge << 6) + u;             // column in [0,256)
    const int seq  = blockIdx.x;
    const long tokbase = (long)seq * TSEQ;

    // activation: a = m1 * sigmoid(m1*z) + m0  ->  sigmoid (ge!=2) or tanh (ge==2)
    const float m1 = (ge == 2) ? 2.0f : 1.0f;
    const float m0 = (ge == 2) ? -1.0f : 0.0f;

    // stage all tokens for this sequence (2 KB LDS)
    tokbuf[tid]       = tokens[tokbase + tid];
    tokbuf[tid + 256] = tokens[tokbase + tid + 256];

    float wk[EMB];
#pragma unroll
    for (int k = 0; k < EMB; ++k) wk[k] = Wk[k * 256 + col];
    float wr[HID];
#pragma unroll
    for (int k = 0; k < HID; ++k) wr[k] = Wr[k * 256 + col];
    const float bz = bias[col];

    if (tid < HID) hbuf[0][tid] = 0.0f;
    __syncthreads();                             // tokbuf visible
    if (tid < EMB) {
        const int tok0 = tokbuf[0];
        xbuf[0][tid] = emb[(long)tok0 * EMB + tid];
    }

    float c = 0.0f;

    for (int t = 0; t < TSEQ; ++t) {
        const int cur = t & 1, nxt = cur ^ 1;
        __syncthreads();
        // prefetch x_{t+1} into the other buffer (wave 0, lanes 0..31)
        if (tid < EMB) {
            const int tn = (t + 1 < TSEQ) ? (t + 1) : t;
            const int tok = tokbuf[tn];
            xbuf[nxt][tid] = emb[(long)tok * EMB + tid];
        }

        float z = bz;
#pragma unroll
        for (int kk = 0; kk < EMB / 4; ++kk) {
            const float4 x4 = *(const float4*)&xbuf[cur][kk * 4];
            z = fmaf(x4.x, wk[kk * 4 + 0], z);
            z = fmaf(x4.y, wk[kk * 4 + 1], z);
            z = fmaf(x4.z, wk[kk * 4 + 2], z);
            z = fmaf(x4.w, wk[kk * 4 + 3], z);
        }
#pragma unroll
        for (int kk = 0; kk < HID / 4; ++kk) {
            const float4 h4 = *(const float4*)&hbuf[cur][kk * 4];
            z = fmaf(h4.x, wr[kk * 4 + 0], z);
            z = fmaf(h4.y, wr[kk * 4 + 1], z);
            z = fmaf(h4.z, wr[kk * 4 + 2], z);
            z = fmaf(h4.w, wr[kk * 4 + 3], z);
        }

        // gate activation (branch-free: tanh(z) = 2*sigmoid(2z)-1)
        const float sg = 1.0f / (1.0f + __expf(-m1 * z));
        const float a  = fmaf(m1, sg, m0);

        // static quad broadcast: lane j reads lane (j&~3)+g  (BitMode swizzle,
        // offset = (or<<5)|0x1C; quads never cross the 32-lane half)
        const float gi = __int_as_float(__builtin_amdgcn_ds_swizzle(__float_as_int(a), 0x001C));
        const float gf = __int_as_float(__builtin_amdgcn_ds_swizzle(__float_as_int(a), 0x003C));
        const float gg = __int_as_float(__builtin_amdgcn_ds_swizzle(__float_as_int(a), 0x005C));
        const float go = __int_as_float(__builtin_amdgcn_ds_swizzle(__float_as_int(a), 0x007C));

        c = fmaf(gf, c, gi * gg);                                 // c = f*c + i*tanh(g)
        const float e2 = __expf(-2.0f * c);
        const float th = fmaf(2.0f, 1.0f / (1.0f + e2), -1.0f);   // tanh(c)
        const float h  = go * th;
        if (ge == 0) hbuf[nxt][u] = h;                            // one writer per unit
    }

    __syncthreads();
    const float* hfin = hbuf[TSEQ & 1];

    if (tid < NCLS) {
        float acc = bd[tid];
#pragma unroll 8
        for (int k = 0; k < HID; ++k) acc = fmaf(hfin[k], Wd[k * NCLS + tid], acc);
        lg[tid] = acc;
    }
    __syncthreads();
    if (tid < NCLS) {
        const float l0 = lg[0], l1 = lg[1], l2 = lg[2];
        const float mm = fmaxf(l0, fmaxf(l1, l2));
        const float e0 = __expf(l0 - mm), e1 = __expf(l1 - mm), e2s = __expf(l2 - mm);
        out[seq * NCLS + tid] = __expf(lg[tid] - mm) / (e0 + e1 + e2s);
    }
}

extern "C" void kernel_launch(void* const* d_in, const int* in_sizes, int n_in,
                              void* d_out, int out_size, void* d_ws, size_t ws_size,
                              hipStream_t stream) {
    const int*   tokens = (const int*)  d_in[0];
    const float* emb    = (const float*)d_in[1];
    const float* Wk     = (const float*)d_in[2];
    const float* Wr     = (const float*)d_in[3];
    const float* b      = (const float*)d_in[4];
    const float* Wd     = (const float*)d_in[5];
    const float* bd     = (const float*)d_in[6];
    float* out = (float*)d_out;

    lstm_fused_kernel<<<dim3(BATCH), dim3(256), 0, stream>>>(
        tokens, emb, Wk, Wr, b, Wd, bd, out);
}

// Round 3
// 365.773 us; speedup vs baseline: 1.4568x; 1.3839x over previous
//
#include <hip/hip_runtime.h>

// emb-lookup -> LSTM(64) over T=512 -> Dense(3) -> softmax.  512 blocks x 256 thr.
// Quad = one hidden unit's 4 gate-columns (i,f,g,o). Lane j of quad reads h-slice
// [16j,16j+16) from LDS (4 x ds_read_b128, 2-way bank alias = free), computes
// partial dots for all 4 gate cols with v_pk_fma_f32, quad-allreduce + gate
// broadcast via DPP quad_perm (VALU pipe, no LDS). x-projection precomputed as
// embWk[VOCAB][256] table in d_ws (one prefetched global load/lane/step);
// fallback without table if ws is too small. Weights pinned in VGPRs via asm.

#define VOCAB 50000
#define EMB 32
#define HID 64
#define NCLS 3
#define BATCH 512
#define TSEQ 512
#define FOURH 256

typedef float v2f __attribute__((ext_vector_type(2)));

#define DPP_XOR1 0xB1  // quad_perm [1,0,3,2]
#define DPP_XOR2 0x4E  // quad_perm [2,3,0,1]
#define DPP_BC0  0x00  // quad_perm [0,0,0,0]
#define DPP_BC1  0x55
#define DPP_BC2  0xAA
#define DPP_BC3  0xFF

template <int CTRL>
__device__ __forceinline__ float dpp_mov(float x) {
    int yi = __builtin_amdgcn_mov_dpp(__builtin_bit_cast(int, x), CTRL, 0xF, 0xF, true);
    return __builtin_bit_cast(float, yi);
}

__device__ __forceinline__ void pin2(v2f& w) {
    double d = __builtin_bit_cast(double, w);
    asm volatile("" : "+v"(d));
    w = __builtin_bit_cast(v2f, d);
}

__global__ __launch_bounds__(256)
void build_table_kernel(const float* __restrict__ emb, const float* __restrict__ Wk,
                        float* __restrict__ table) {
    __shared__ float e[EMB];
    const int c = threadIdx.x;
    for (int v = blockIdx.x; v < VOCAB; v += gridDim.x) {
        __syncthreads();
        if (c < EMB) e[c] = emb[v * EMB + c];
        __syncthreads();
        float acc = 0.0f;
#pragma unroll
        for (int k = 0; k < EMB; ++k) acc = fmaf(e[k], Wk[k * FOURH + c], acc);
        table[(long)v * FOURH + c] = acc;
    }
}

template <bool USE_TABLE>
__global__ __launch_bounds__(256)
void lstm_kernel(const int* __restrict__ tokens, const float* __restrict__ emb,
                 const float* __restrict__ Wk, const float* __restrict__ Wr,
                 const float* __restrict__ bias, const float* __restrict__ Wd,
                 const float* __restrict__ bd, const float* __restrict__ table,
                 float* __restrict__ out)
{
    __shared__ __align__(16) float hbuf[2][HID];
    __shared__ __align__(16) float xbuf[2][EMB];
    __shared__ float lg[NCLS];

    const int tid = threadIdx.x;
    const int w   = tid >> 6;
    const int l   = tid & 63;
    const int q   = l >> 2;
    const int j   = l & 3;              // gate of this lane AND k-slice id
    const int u   = (w << 4) + q;       // hidden unit 0..63
    const int seq = blockIdx.x;
    const long tokbase = (long)seq * TSEQ;

    const int   colj  = u + (j << 6);   // this lane's own gate column
    const float bmine = bias[colj];
    const float m1 = (j == 2) ? 2.0f : 1.0f;   // tanh for g-gate via 2*sig(2z)-1
    const float m0 = (j == 2) ? -1.0f : 0.0f;

    // ---- load + pin recurrent weights: 4 cols x 16 k -> 32 float2 regs ----
    v2f wr2[4][8];
#pragma unroll
    for (int g = 0; g < 4; ++g)
#pragma unroll
        for (int m = 0; m < 8; ++m) {
            const int k = (j << 4) + 2 * m;
            const int cc = u + (g << 6);
            v2f t; t.x = Wr[k * FOURH + cc]; t.y = Wr[(k + 1) * FOURH + cc];
            wr2[g][m] = t; pin2(wr2[g][m]);
        }

    v2f wk2[4][4];
    if (!USE_TABLE) {
#pragma unroll
        for (int g = 0; g < 4; ++g)
#pragma unroll
            for (int m = 0; m < 4; ++m) {
                const int k = (j << 3) + 2 * m;
                const int cc = u + (g << 6);
                v2f t; t.x = Wk[k * FOURH + cc]; t.y = Wk[(k + 1) * FOURH + cc];
                wk2[g][m] = t; pin2(wk2[g][m]);
            }
    }

    // ---- prologue: h=0, first x/zx ----
    if (tid < HID) hbuf[0][tid] = 0.0f;
    const int tok0 = tokens[tokbase];
    float zx_cur = 0.0f;
    if (USE_TABLE) {
        zx_cur = table[(long)tok0 * FOURH + colj];
    } else if (tid < 8) {
        ((float4*)&xbuf[0][0])[tid] = ((const float4*)(emb + (long)tok0 * EMB))[tid];
    }
    __syncthreads();

    float c = 0.0f;

    for (int t = 0; t < TSEQ; ++t) {
        const int cur = t & 1, nxt = cur ^ 1;
        const int tn   = (t + 1 < TSEQ) ? t + 1 : t;
        const int tokn = tokens[tokbase + tn];      // uniform -> s_load

        float zx_next = 0.0f;
        if (USE_TABLE) {
            zx_next = table[(long)tokn * FOURH + colj];   // prefetch, used next iter
        } else if (tid < 8) {
            ((float4*)&xbuf[nxt][0])[tid] = ((const float4*)(emb + (long)tokn * EMB))[tid];
        }

        // ---- partial dots for the quad's 4 gate columns ----
        v2f a0 = {0.f, 0.f}, a1 = {0.f, 0.f}, a2 = {0.f, 0.f}, a3 = {0.f, 0.f};

        const float4* hp = (const float4*)&hbuf[cur][j << 4];
        float4 h0 = hp[0], h1 = hp[1], h2 = hp[2], h3 = hp[3];
        v2f hh[8];
        hh[0].x=h0.x; hh[0].y=h0.y; hh[1].x=h0.z; hh[1].y=h0.w;
        hh[2].x=h1.x; hh[2].y=h1.y; hh[3].x=h1.z; hh[3].y=h1.w;
        hh[4].x=h2.x; hh[4].y=h2.y; hh[5].x=h2.z; hh[5].y=h2.w;
        hh[6].x=h3.x; hh[6].y=h3.y; hh[7].x=h3.z; hh[7].y=h3.w;
#pragma unroll
        for (int m = 0; m < 8; ++m) {
            a0 = __builtin_elementwise_fma(hh[m], wr2[0][m], a0);
            a1 = __builtin_elementwise_fma(hh[m], wr2[1][m], a1);
            a2 = __builtin_elementwise_fma(hh[m], wr2[2][m], a2);
            a3 = __builtin_elementwise_fma(hh[m], wr2[3][m], a3);
        }
        if (!USE_TABLE) {
            const float4* xp = (const float4*)&xbuf[cur][j << 3];
            float4 x0 = xp[0], x1 = xp[1];
            v2f xx[4];
            xx[0].x=x0.x; xx[0].y=x0.y; xx[1].x=x0.z; xx[1].y=x0.w;
            xx[2].x=x1.x; xx[2].y=x1.y; xx[3].x=x1.z; xx[3].y=x1.w;
#pragma unroll
            for (int m = 0; m < 4; ++m) {
                a0 = __builtin_elementwise_fma(xx[m], wk2[0][m], a0);
                a1 = __builtin_elementwise_fma(xx[m], wk2[1][m], a1);
                a2 = __builtin_elementwise_fma(xx[m], wk2[2][m], a2);
                a3 = __builtin_elementwise_fma(xx[m], wk2[3][m], a3);
            }
        }

        float p0 = a0.x + a0.y, p1 = a1.x + a1.y, p2 = a2.x + a2.y, p3 = a3.x + a3.y;

        // own-column extra (zx + bias), added exactly once per column (by lane j)
        const float add_own = (USE_TABLE ? zx_cur : 0.0f) + bmine;
        p0 += (j == 0) ? add_own : 0.0f;
        p1 += (j == 1) ? add_own : 0.0f;
        p2 += (j == 2) ? add_own : 0.0f;
        p3 += (j == 3) ? add_own : 0.0f;

        // quad allreduce (DPP, VALU pipe)
        p0 += dpp_mov<DPP_XOR1>(p0); p0 += dpp_mov<DPP_XOR2>(p0);
        p1 += dpp_mov<DPP_XOR1>(p1); p1 += dpp_mov<DPP_XOR2>(p1);
        p2 += dpp_mov<DPP_XOR1>(p2); p2 += dpp_mov<DPP_XOR2>(p2);
        p3 += dpp_mov<DPP_XOR1>(p3); p3 += dpp_mov<DPP_XOR2>(p3);

        // activate own gate, broadcast all 4 across the quad
        const float zown = (j < 2) ? ((j == 0) ? p0 : p1) : ((j == 2) ? p2 : p3);
        const float act  = fmaf(m1, 1.0f / (1.0f + __expf(-m1 * zown)), m0);
        const float gi = dpp_mov<DPP_BC0>(act);
        const float gf = dpp_mov<DPP_BC1>(act);
        const float gg = dpp_mov<DPP_BC2>(act);
        const float go = dpp_mov<DPP_BC3>(act);

        c = fmaf(gf, c, gi * gg);
        const float th = fmaf(2.0f, 1.0f / (1.0f + __expf(-2.0f * c)), -1.0f);
        const float h  = go * th;
        if (j == 0) hbuf[nxt][u] = h;

        zx_cur = zx_next;
        __syncthreads();
    }

    const float* hfin = hbuf[TSEQ & 1];
    if (tid < NCLS) {
        float acc = bd[tid];
#pragma unroll 8
        for (int k = 0; k < HID; ++k) acc = fmaf(hfin[k], Wd[k * NCLS + tid], acc);
        lg[tid] = acc;
    }
    __syncthreads();
    if (tid < NCLS) {
        const float l0 = lg[0], l1 = lg[1], l2 = lg[2];
        const float mm = fmaxf(l0, fmaxf(l1, l2));
        const float e0 = __expf(l0 - mm), e1 = __expf(l1 - mm), e2 = __expf(l2 - mm);
        out[seq * NCLS + tid] = __expf(lg[tid] - mm) / (e0 + e1 + e2);
    }
}

extern "C" void kernel_launch(void* const* d_in, const int* in_sizes, int n_in,
                              void* d_out, int out_size, void* d_ws, size_t ws_size,
                              hipStream_t stream) {
    const int*   tokens = (const int*)  d_in[0];
    const float* emb    = (const float*)d_in[1];
    const float* Wk     = (const float*)d_in[2];
    const float* Wr     = (const float*)d_in[3];
    const float* b      = (const float*)d_in[4];
    const float* Wd     = (const float*)d_in[5];
    const float* bd     = (const float*)d_in[6];
    float* out = (float*)d_out;

    const size_t need = (size_t)VOCAB * FOURH * sizeof(float);
    if (ws_size >= need) {
        float* table = (float*)d_ws;
        build_table_kernel<<<dim3(1024), dim3(256), 0, stream>>>(emb, Wk, table);
        lstm_kernel<true><<<dim3(BATCH), dim3(256), 0, stream>>>(
            tokens, emb, Wk, Wr, b, Wd, bd, table, out);
    } else {
        lstm_kernel<false><<<dim3(BATCH), dim3(256), 0, stream>>>(
            tokens, emb, Wk, Wr, b, Wd, bd, nullptr, out);
    }
}

// Round 4
// 306.612 us; speedup vs baseline: 1.7378x; 1.1930x over previous
//
#include <hip/hip_runtime.h>

// emb-lookup -> LSTM(64) over T=512 -> Dense(3) -> softmax.  512 blocks x 256 thr.
// Quad = one hidden unit's 4 gate cols (i,f,g,o). Lane j of quad: k-slice
// [16j,16j+16) of h (4 x ds_read_b128, broadcast), partial dots for all 4 gate
// cols via v_pk_fma_f32, quad allreduce + gate broadcast via DPP quad_perm.
// x-projection (+bias) precomputed as table[VOCAB][256] in d_ws, prefetched 2
// steps ahead. Weights pinned in VGPRs by an IN-LOOP asm tie (R3's load-time
// pin let RA spill them: VGPR=48 < 64 needed -> scratch reloads every step).

#define VOCAB 50000
#define EMB 32
#define HID 64
#define NCLS 3
#define BATCH 512
#define TSEQ 512
#define FOURH 256
#define LOG2E 1.4426950408889634f

typedef float v2f __attribute__((ext_vector_type(2)));

#define DPP_XOR1 0xB1  // quad_perm [1,0,3,2]
#define DPP_XOR2 0x4E  // quad_perm [2,3,0,1]
#define DPP_BC0  0x00
#define DPP_BC1  0x55
#define DPP_BC2  0xAA
#define DPP_BC3  0xFF

template <int CTRL>
__device__ __forceinline__ float dpp_mov(float x) {
    int y = __builtin_amdgcn_mov_dpp(__builtin_bit_cast(int, x), CTRL, 0xF, 0xF, true);
    return __builtin_bit_cast(float, y);
}
__device__ __forceinline__ float qred(float p) {   // quad allreduce (fusable to v_add_f32_dpp)
    p += dpp_mov<DPP_XOR1>(p);
    p += dpp_mov<DPP_XOR2>(p);
    return p;
}
__device__ __forceinline__ v2f asv2(double d) { return __builtin_bit_cast(v2f, d); }
__device__ __forceinline__ double asd(v2f v)  { return __builtin_bit_cast(double, v); }

#define PIN8(A) asm volatile("" : "+v"(A[0]), "+v"(A[1]), "+v"(A[2]), "+v"(A[3]), \
                                  "+v"(A[4]), "+v"(A[5]), "+v"(A[6]), "+v"(A[7]))
#define PIN4(A) asm volatile("" : "+v"(A[0]), "+v"(A[1]), "+v"(A[2]), "+v"(A[3]))

// table[v][c] = emb[v,:] @ Wk[:,c] + bias[c].  Wk column register-resident per thread.
__global__ __launch_bounds__(256)
void build_table_kernel(const float* __restrict__ emb, const float* __restrict__ Wk,
                        const float* __restrict__ bias, float* __restrict__ table) {
    const int c = threadIdx.x;
    const float bb = bias[c];
    float wcol[EMB];
#pragma unroll
    for (int k = 0; k < EMB; ++k) wcol[k] = Wk[k * FOURH + c];
    for (int v = blockIdx.x; v < VOCAB; v += gridDim.x) {
        const float4* er = (const float4*)(emb + (long)v * EMB);
        float acc = bb;
#pragma unroll
        for (int kk = 0; kk < EMB / 4; ++kk) {
            const float4 e = er[kk];
            acc = fmaf(e.x, wcol[kk * 4 + 0], acc);
            acc = fmaf(e.y, wcol[kk * 4 + 1], acc);
            acc = fmaf(e.z, wcol[kk * 4 + 2], acc);
            acc = fmaf(e.w, wcol[kk * 4 + 3], acc);
        }
        table[(long)v * FOURH + c] = acc;
    }
}

template <bool USE_TABLE>
__global__ __launch_bounds__(256, 2)
void lstm_kernel(const int* __restrict__ tokens, const float* __restrict__ emb,
                 const float* __restrict__ Wk, const float* __restrict__ Wr,
                 const float* __restrict__ bias, const float* __restrict__ Wd,
                 const float* __restrict__ bd, const float* __restrict__ table,
                 float* __restrict__ out)
{
    __shared__ __align__(16) float hbuf[2][HID];
    __shared__ __align__(16) float xbuf[2][EMB];
    __shared__ float lg[NCLS];

    const int tid = threadIdx.x;
    const int w   = tid >> 6;
    const int l   = tid & 63;
    const int q   = l >> 2;
    const int j   = l & 3;              // gate AND k-slice id
    const int u   = (w << 4) + q;       // hidden unit 0..63
    const int seq = blockIdx.x;
    const long tokbase = (long)seq * TSEQ;
    const int colj = u + (j << 6);

    const float m1 = (j == 2) ? 2.0f : 1.0f;   // tanh(g) = 2*sigmoid(2g)-1
    const float m0 = (j == 2) ? -1.0f : 0.0f;
    const float nm1l = -m1 * LOG2E;

    // recurrent weights: 4 cols x 16 k -> 32 double-packed v2f
    double wrd[4][8];
#pragma unroll
    for (int g = 0; g < 4; ++g)
#pragma unroll
        for (int m = 0; m < 8; ++m) {
            const int k = (j << 4) + 2 * m;
            const int cc = u + (g << 6);
            v2f t; t.x = Wr[k * FOURH + cc]; t.y = Wr[(k + 1) * FOURH + cc];
            wrd[g][m] = asd(t);
        }

    double wkd[4][4];
    float bmine = 0.0f;
    if (!USE_TABLE) {
        bmine = bias[colj];
#pragma unroll
        for (int g = 0; g < 4; ++g)
#pragma unroll
            for (int m = 0; m < 4; ++m) {
                const int k = (j << 3) + 2 * m;
                const int cc = u + (g << 6);
                v2f t; t.x = Wk[k * FOURH + cc]; t.y = Wk[(k + 1) * FOURH + cc];
                wkd[g][m] = asd(t);
            }
    }

    if (tid < HID) hbuf[0][tid] = 0.0f;
    float zxA = 0.0f, zxB = 0.0f;
    if (USE_TABLE) {
        const int t0 = tokens[tokbase], t1 = tokens[tokbase + 1];
        zxA = table[(long)t0 * FOURH + colj];
        zxB = table[(long)t1 * FOURH + colj];
    } else {
        if (tid < 8)
            ((float4*)&xbuf[0][0])[tid] = ((const float4*)(emb + (long)tokens[tokbase] * EMB))[tid];
    }
    __syncthreads();

    float c = 0.0f;

    for (int t = 0; t < TSEQ; ++t) {
        const int cur = t & 1, nxt = cur ^ 1;

        // force weight residency every iteration (reload would be >= this cost)
        PIN8(wrd[0]); PIN8(wrd[1]); PIN8(wrd[2]); PIN8(wrd[3]);
        if (!USE_TABLE) { PIN4(wkd[0]); PIN4(wkd[1]); PIN4(wkd[2]); PIN4(wkd[3]); }

        float zxC = 0.0f;
        if (USE_TABLE) {
            const int tn  = (t + 2 < TSEQ) ? t + 2 : TSEQ - 1;
            const int tok = tokens[tokbase + tn];
            zxC = table[(long)tok * FOURH + colj];       // used at step t+2
        } else {
            const int tn  = (t + 1 < TSEQ) ? t + 1 : TSEQ - 1;
            const int tok = tokens[tokbase + tn];
            if (tid < 8)
                ((float4*)&xbuf[nxt][0])[tid] = ((const float4*)(emb + (long)tok * EMB))[tid];
        }

        const float4* hp = (const float4*)&hbuf[cur][j << 4];
        const float4 h0 = hp[0], h1 = hp[1], h2 = hp[2], h3 = hp[3];
        v2f hh[8];
        hh[0] = (v2f){h0.x, h0.y}; hh[1] = (v2f){h0.z, h0.w};
        hh[2] = (v2f){h1.x, h1.y}; hh[3] = (v2f){h1.z, h1.w};
        hh[4] = (v2f){h2.x, h2.y}; hh[5] = (v2f){h2.z, h2.w};
        hh[6] = (v2f){h3.x, h3.y}; hh[7] = (v2f){h3.z, h3.w};

        v2f a0 = {0.f, 0.f}, a1 = {0.f, 0.f}, a2 = {0.f, 0.f}, a3 = {0.f, 0.f};
#pragma unroll
        for (int m = 0; m < 8; ++m) {
            a0 = __builtin_elementwise_fma(hh[m], asv2(wrd[0][m]), a0);
            a1 = __builtin_elementwise_fma(hh[m], asv2(wrd[1][m]), a1);
            a2 = __builtin_elementwise_fma(hh[m], asv2(wrd[2][m]), a2);
            a3 = __builtin_elementwise_fma(hh[m], asv2(wrd[3][m]), a3);
        }
        if (!USE_TABLE) {
            const float4* xp = (const float4*)&xbuf[cur][j << 3];
            const float4 x0 = xp[0], x1 = xp[1];
            v2f xx[4];
            xx[0] = (v2f){x0.x, x0.y}; xx[1] = (v2f){x0.z, x0.w};
            xx[2] = (v2f){x1.x, x1.y}; xx[3] = (v2f){x1.z, x1.w};
#pragma unroll
            for (int m = 0; m < 4; ++m) {
                a0 = __builtin_elementwise_fma(xx[m], asv2(wkd[0][m]), a0);
                a1 = __builtin_elementwise_fma(xx[m], asv2(wkd[1][m]), a1);
                a2 = __builtin_elementwise_fma(xx[m], asv2(wkd[2][m]), a2);
                a3 = __builtin_elementwise_fma(xx[m], asv2(wkd[3][m]), a3);
            }
        }

        float p0 = qred(a0.x + a0.y);
        float p1 = qred(a1.x + a1.y);
        float p2 = qred(a2.x + a2.y);
        float p3 = qred(a3.x + a3.y);

        float zown = (j < 2) ? ((j == 0) ? p0 : p1) : ((j == 2) ? p2 : p3);
        zown += USE_TABLE ? zxA : bmine;

        // own-gate activation: sigmoid (or tanh for g via m1/m0 fold)
        const float sg  = __builtin_amdgcn_rcpf(1.0f + __builtin_amdgcn_exp2f(nm1l * zown));
        const float act = fmaf(m1, sg, m0);

        const float gi = dpp_mov<DPP_BC0>(act);
        const float gf = dpp_mov<DPP_BC1>(act);
        const float gg = dpp_mov<DPP_BC2>(act);
        const float go = dpp_mov<DPP_BC3>(act);

        c = fmaf(gf, c, gi * gg);
        const float th = fmaf(2.0f,
            __builtin_amdgcn_rcpf(1.0f + __builtin_amdgcn_exp2f(c * (-2.0f * LOG2E))), -1.0f);
        const float h = go * th;
        if (j == 0) hbuf[nxt][u] = h;

        zxA = zxB; zxB = zxC;
        __syncthreads();
    }

    const float* hfin = hbuf[TSEQ & 1];
    if (tid < NCLS) {
        float acc = bd[tid];
#pragma unroll 8
        for (int k = 0; k < HID; ++k) acc = fmaf(hfin[k], Wd[k * NCLS + tid], acc);
        lg[tid] = acc;
    }
    __syncthreads();
    if (tid < NCLS) {
        const float l0 = lg[0], l1 = lg[1], l2 = lg[2];
        const float mm = fmaxf(l0, fmaxf(l1, l2));
        const float e0 = __expf(l0 - mm), e1 = __expf(l1 - mm), e2 = __expf(l2 - mm);
        out[seq * NCLS + tid] = __expf(lg[tid] - mm) / (e0 + e1 + e2);
    }
}

extern "C" void kernel_launch(void* const* d_in, const int* in_sizes, int n_in,
                              void* d_out, int out_size, void* d_ws, size_t ws_size,
                              hipStream_t stream) {
    const int*   tokens = (const int*)  d_in[0];
    const float* emb    = (const float*)d_in[1];
    const float* Wk     = (const float*)d_in[2];
    const float* Wr     = (const float*)d_in[3];
    const float* b      = (const float*)d_in[4];
    const float* Wd     = (const float*)d_in[5];
    const float* bd     = (const float*)d_in[6];
    float* out = (float*)d_out;

    const size_t need = (size_t)VOCAB * FOURH * sizeof(float);
    if (ws_size >= need) {
        float* table = (float*)d_ws;
        build_table_kernel<<<dim3(2048), dim3(256), 0, stream>>>(emb, Wk, b, table);
        lstm_kernel<true><<<dim3(BATCH), dim3(256), 0, stream>>>(
            tokens, emb, Wk, Wr, b, Wd, bd, table, out);
    } else {
        lstm_kernel<false><<<dim3(BATCH), dim3(256), 0, stream>>>(
            tokens, emb, Wk, Wr, b, Wd, bd, nullptr, out);
    }
}